// Round 4
// baseline (82.047 us; speedup 1.0000x reference)
//
#include <hip/hip_runtime.h>
#include <math.h>

#define DIMK 1024
#define BATCH 32
#define YLD 1025       // y / out leading dim (dim+1)
#define DT_C 0.01f
#define NT 512

typedef __attribute__((ext_vector_type(8))) short short8;   // 8 bf16 = 4 VGPRs
typedef __attribute__((ext_vector_type(4))) float f32x4;

static __device__ __forceinline__ unsigned short f2bf(float x) {
    // RNE float -> bf16
    unsigned int u = __float_as_uint(x);
    return (unsigned short)((u + 0x7FFFu + ((u >> 16) & 1u)) >> 16);
}
static __device__ __forceinline__ float bf2f(unsigned short s) {
    return __uint_as_float(((unsigned int)s) << 16);
}

// Swizzled LDS index (ushort units) for Bt[n][j]: XOR row bits into the
// 16B column-block index -> ds_read_b128 across 16 rows hits the 8-phase
// LDS bandwidth floor instead of a 16-lane 4-bank pileup. Keeps 16B align.
static __device__ __forceinline__ int bt_addr(int n, int j) {
    int cb = (j >> 3) ^ (n & 7);
    return n * DIMK + cb * 8 + (j & 7);
}

// Fully fused: sin/cos -> LDS, A fp32->bf16 in-reg, MFMA GEMM, epilogue, f1.
// 64 blocks x 512 thr (8 waves: kh = w>>2 k-half, nt = w&3 n-tile).
__global__ __launch_bounds__(NT) void kura_fused(
    const float* __restrict__ t,
    const float* __restrict__ y,
    const float* __restrict__ u,
    const float* __restrict__ A,
    const float* __restrict__ freqs,
    float* __restrict__ out) {
    __shared__ unsigned short Bt[64 * DIMK];   // 128 KB, swizzled; rows 0..31 sin, 32..63 cos
    __shared__ float Cls[2][64][17];           // [khalf][n][i_local], padded
    __shared__ float red[8];

    const int tid = threadIdx.x;
    const int idx = (int)floorf(t[0] / DT_C);
    const float* uslice = u + (size_t)idx * BATCH * DIMK;

    // ---- Phase 1: Bt[b][j]=sin(y[b,j]), Bt[b+32][j]=cos; 4 j per thread-iter.
    #pragma unroll
    for (int q = 0; q < 16; ++q) {
        int li = q * NT + tid;                 // quad index, 0..8191
        int b = li >> 8;
        int j = (li & 255) * 4;
        const float* yp = y + (size_t)b * YLD + j;
        float p0 = yp[0], p1 = yp[1], p2 = yp[2], p3 = yp[3];
        ushort4 sv, cv;
        sv.x = f2bf(__sinf(p0)); cv.x = f2bf(__cosf(p0));
        sv.y = f2bf(__sinf(p1)); cv.y = f2bf(__cosf(p1));
        sv.z = f2bf(__sinf(p2)); cv.z = f2bf(__cosf(p2));
        sv.w = f2bf(__sinf(p3)); cv.w = f2bf(__cosf(p3));
        *(ushort4*)&Bt[bt_addr(b, j)]      = sv;   // (j&7)∈{0,4} -> 8B aligned
        *(ushort4*)&Bt[bt_addr(b + 32, j)] = cv;
    }

    // ---- f1 partial (blocks 0..31 own batch b = blockIdx.x)
    float f1a = 0.f;
    if (blockIdx.x < BATCH) {
        const float* ub = uslice + (size_t)blockIdx.x * DIMK;
        float2 v = *(const float2*)(ub + tid * 2);
        f1a = fmaf(v.x, v.x, v.y * v.y);
    }
    for (int off = 32; off > 0; off >>= 1)
        f1a += __shfl_down(f1a, off, 64);
    if ((tid & 63) == 0) red[tid >> 6] = f1a;

    __syncthreads();                           // Bt + red ready

    if (tid == 0 && blockIdx.x < BATCH) {
        float s = 0.f;
        #pragma unroll
        for (int q = 0; q < 8; ++q) s += red[q];
        out[(size_t)blockIdx.x * YLD + DIMK] = s;
    }

    // ---- Phase 2: GEMM. D[i][n] = sum_j A[i][j]*Bt[n][j], strip of 16 rows.
    const int l  = tid & 63;
    const int w  = tid >> 6;
    const int nl = l & 15;                     // A-row / B-row within tile
    const int gr = l >> 4;                     // k-group 0..3
    const int nt = w & 3;                      // n-tile
    const int kh = w >> 2;                     // k-half
    const int i0 = blockIdx.x * 16;
    const float* Arow = A + (size_t)(i0 + nl) * DIMK + kh * 512 + gr * 8;
    const int brow = nt * 16 + nl;

    f32x4 acc = {0.f, 0.f, 0.f, 0.f};
    #pragma unroll 8
    for (int ks = 0; ks < 16; ++ks) {          // 512 k per half / 32
        float4 a0 = *(const float4*)(Arow + ks * 32);
        float4 a1 = *(const float4*)(Arow + ks * 32 + 4);
        short8 av;
        av[0] = (short)f2bf(a0.x); av[1] = (short)f2bf(a0.y);
        av[2] = (short)f2bf(a0.z); av[3] = (short)f2bf(a0.w);
        av[4] = (short)f2bf(a1.x); av[5] = (short)f2bf(a1.y);
        av[6] = (short)f2bf(a1.z); av[7] = (short)f2bf(a1.w);
        int kcol = kh * 512 + ks * 32 + gr * 8;
        short8 bv = *(const short8*)&Bt[bt_addr(brow, kcol)];  // 16B aligned
        acc = __builtin_amdgcn_mfma_f32_16x16x32_bf16(av, bv, acc, 0, 0, 0);
    }

    // C/D layout: col (lane&15) = n_local, row ((lane>>4)*4+reg) = i_local
    #pragma unroll
    for (int tt = 0; tt < 4; ++tt)
        Cls[kh][nt * 16 + nl][gr * 4 + tt] = acc[tt];
    __syncthreads();

    // ---- Epilogue: one (b, i) pair per thread
    {
        int b = tid >> 4;
        int i = tid & 15;
        float aS = Cls[0][b][i]      + Cls[1][b][i];
        float aC = Cls[0][b + 32][i] + Cls[1][b + 32][i];
        float sp = bf2f(Bt[bt_addr(b, i0 + i)]);
        float cp = bf2f(Bt[bt_addr(b + 32, i0 + i)]);
        float cf = uslice[(size_t)b * DIMK + i0 + i];
        out[(size_t)b * YLD + i0 + i] =
            fmaf(cf * (cp * aS - sp * aC), 1.0f / (float)DIMK, freqs[i0 + i]);
    }
}

extern "C" void kernel_launch(void* const* d_in, const int* in_sizes, int n_in,
                              void* d_out, int out_size, void* d_ws, size_t ws_size,
                              hipStream_t stream) {
    const float* t     = (const float*)d_in[0];   // (1,)
    const float* y     = (const float*)d_in[1];   // (32, 1025)
    const float* u     = (const float*)d_in[2];   // (100, 32, 1024)
    const float* A     = (const float*)d_in[3];   // (1024, 1024)
    const float* freqs = (const float*)d_in[4];   // (1024,)
    float* out = (float*)d_out;                   // (32, 1025)

    kura_fused<<<DIMK / 16, NT, 0, stream>>>(t, y, u, A, freqs, out);
}